// Round 2
// baseline (11503.531 us; speedup 1.0000x reference)
//
#include <hip/hip_runtime.h>
#include <stdint.h>

#define B_  32
#define S_  32
#define V_  100
#define HD_ 32
#define HID_ 64
#define ND_ 10
#define NROW (B_*V_)

// ---------------- threefry2x32 (JAX-compatible) ----------------
__host__ __device__ inline void tf2x32(uint32_t k0, uint32_t k1,
                                       uint32_t& x0, uint32_t& x1) {
  uint32_t ks0 = k0, ks1 = k1, ks2 = k0 ^ k1 ^ 0x1BD11BDAu;
#define TFR(r) { x0 += x1; x1 = (x1 << (r)) | (x1 >> (32 - (r))); x1 ^= x0; }
  x0 += ks0; x1 += ks1;
  TFR(13) TFR(15) TFR(26) TFR(6)
  x0 += ks1; x1 += ks2 + 1u;
  TFR(17) TFR(29) TFR(16) TFR(24)
  x0 += ks2; x1 += ks0 + 2u;
  TFR(13) TFR(15) TFR(26) TFR(6)
  x0 += ks0; x1 += ks1 + 3u;
  TFR(17) TFR(29) TFR(16) TFR(24)
  x0 += ks1; x1 += ks2 + 4u;
  TFR(13) TFR(15) TFR(26) TFR(6)
  x0 += ks2; x1 += ks0 + 5u;
#undef TFR
}

// ---------------- erfinv (XLA / Giles f32 polynomial) ----------------
__device__ __forceinline__ float erfinv_f(float x) {
  float w = -log1pf(-x * x);
  float p;
  if (w < 5.0f) {
    w -= 2.5f;
    p = 2.81022636e-08f;
    p = fmaf(p, w, 3.43273939e-07f);
    p = fmaf(p, w, -3.5233877e-06f);
    p = fmaf(p, w, -4.39150654e-06f);
    p = fmaf(p, w, 0.00021858087f);
    p = fmaf(p, w, -0.00125372503f);
    p = fmaf(p, w, -0.00417768164f);
    p = fmaf(p, w, 0.246640727f);
    p = fmaf(p, w, 1.50140941f);
  } else {
    w = sqrtf(w) - 3.0f;
    p = -0.000200214257f;
    p = fmaf(p, w, 0.000100950558f);
    p = fmaf(p, w, 0.00134934322f);
    p = fmaf(p, w, -0.00367342844f);
    p = fmaf(p, w, 0.00573950773f);
    p = fmaf(p, w, -0.0076224613f);
    p = fmaf(p, w, 0.00943887047f);
    p = fmaf(p, w, 1.00167406f);
    p = fmaf(p, w, 2.83297682f);
  }
  return p * x;
}

__device__ __forceinline__ float softplus_f(float x) {
  // jnp.logaddexp(x, 0)
  return fmaxf(x, 0.0f) + log1pf(expf(-fabsf(x)));
}

// out = a + sum_{k<4*K4} x[k] * W[k*O + lane];  W global row-major, x in LDS (broadcast)
template<int K4, int O>
__device__ __forceinline__ float dotWxT(const float* __restrict__ W,
                                        const float* __restrict__ x,
                                        float a, int lane) {
#pragma unroll
  for (int kb = 0; kb < K4; ++kb) {
    float4 xv = *(const float4*)(x + kb * 4);
    a = fmaf(xv.x, W[(kb * 4 + 0) * O + lane], a);
    a = fmaf(xv.y, W[(kb * 4 + 1) * O + lane], a);
    a = fmaf(xv.z, W[(kb * 4 + 2) * O + lane], a);
    a = fmaf(xv.w, W[(kb * 4 + 3) * O + lane], a);
  }
  return a;
}

struct SubK { uint32_t k[ND_][2]; };

// ---------------- Euler kernel: one interval (10 SDE steps), 1 row/wave ----------------
__launch_bounds__(256)
__global__ void euler_k(const float* __restrict__ time_, const int* __restrict__ type_,
                        const float* __restrict__ mask_,
                        const float* __restrict__ fW1, const float* __restrict__ fb1,
                        const float* __restrict__ fW2, const float* __restrict__ fb2,
                        const float* __restrict__ fW3, const float* __restrict__ fb3,
                        const float* __restrict__ gW1, const float* __restrict__ gb1,
                        const float* __restrict__ gW2, const float* __restrict__ gb2,
                        const float* __restrict__ gW3, const float* __restrict__ gb3,
                        const float* __restrict__ eW1, const float* __restrict__ eb1,
                        const float* __restrict__ eW2, const float* __restrict__ eb2,
                        float* __restrict__ h, float* __restrict__ acc,
                        float* __restrict__ prevl, float* __restrict__ prevt,
                        float* __restrict__ ltlog, float* __restrict__ dout,
                        int s, SubK sk) {
  __shared__ float hls[4][32];
  __shared__ float als[4][64];
  const int w = threadIdx.x >> 6, lane = threadIdx.x & 63;
  const int row = blockIdx.x * 4 + w;
  const int b = row / V_, v = row % V_;

  const float t0 = time_[b * S_ + s - 1];
  const float t1 = time_[b * S_ + s];
  const float dt = (t1 - t0) / 10.0f;
  const float sq = sqrtf(dt);
  const float msk = mask_[b * S_ + s];
  const float mskp = mask_[b * S_ + s - 1];

  if (lane < 32) hls[w][lane] = h[row * HD_ + lane];

  const float fb1r = fb1[lane], fb2r = fb2[lane];
  const float gb1r = gb1[lane], gb2r = gb2[lane];
  const float eb1r = eb1[lane], eW2r = eW2[lane];
  const float eb2r = eb2[0];
  const float fb3r = (lane < 32) ? fb3[lane] : 0.0f;
  const float gb3r = (lane < 32) ? gb3[lane] : 0.0f;

  auto eint = [&]() -> float {
    float a = dotWxT<8, 64>(eW1, hls[w], eb1r, lane);
    float t = tanhf(a) * eW2r;
#pragma unroll
    for (int o = 1; o < 64; o <<= 1) t += __shfl_xor(t, o, 64);
    return softplus_f(t + eb2r);
  };

  float lprev = eint();                 // l_init of this interval
  float accl = acc[row];
  if (s > 1) accl += (prevl[row] * mskp + lprev * msk) * (t0 - prevt[row]) * msk;

  for (int j = 0; j < ND_; ++j) {
    const float dft = dt * (float)(j + 1);
    // f MLP
    float a = dotWxT<8, 64>(fW1, hls[w], fb1r, lane);
    a = fmaf(dft, fW1[32 * HID_ + lane], a);
    a = fmaf(t0,  fW1[33 * HID_ + lane], a);
    als[w][lane] = tanhf(a);
    a = dotWxT<16, 64>(fW2, als[w], fb2r, lane);
    float a2 = tanhf(a);
    als[w][lane] = a2;
    float drift = 0.0f;
    if (lane < 32) drift = dotWxT<16, 32>(fW3, als[w], fb3r, lane);
    // g MLP
    a = dotWxT<8, 64>(gW1, hls[w], gb1r, lane);
    a = fmaf(dft, gW1[32 * HID_ + lane], a);
    als[w][lane] = tanhf(a);
    a = dotWxT<16, 64>(gW2, als[w], gb2r, lane);
    als[w][lane] = tanhf(a);
    float diff = 0.0f;
    if (lane < 32) diff = dotWxT<16, 32>(gW3, als[w], gb3r, lane);
    // noise (JAX partitionable threefry) + h update
    if (lane < 32) {
      uint32_t x0 = 0u, x1 = (uint32_t)(row * HD_ + lane);
      tf2x32(sk.k[j][0], sk.k[j][1], x0, x1);
      uint32_t bits = x0 ^ x1;
      float f = __uint_as_float(0x3f800000u | (bits >> 9)) - 1.0f;
      const float LO = -0.99999994f;
      float u = fmaxf(LO, f * 2.0f + LO);
      float n = 1.4142135f * erfinv_f(u);
      hls[w][lane] = hls[w][lane] + drift * dt + (diff * sq) * n;
    }
    // intensity + trapezoid
    float l = eint();
    float tj  = t0 + dt * (float)j;
    float tj1 = t0 + dt * (float)(j + 1);
    accl += (lprev * msk + l * msk) * ((tj1 - tj) * msk);
    lprev = l;
  }

  if (lane < 32) h[row * HD_ + lane] = hls[w][lane];
  if (lane == 0) {
    acc[row] = accl;
    prevl[row] = lprev;
    prevt[row] = t0 + dt * 10.0f;
    dout[1 + (b * S_ + s) * V_ + v] = lprev;
    int ev = type_[b * S_ + s];
    if (v == ev) ltlog[s * B_ + b] = logf(lprev + 1e-16f) * msk;
  }
}

// ---------------- msg_jump kernel (s==0 also does init: l0, acc=0, lt0) ----------------
__launch_bounds__(256)
__global__ void msg_k(const int* __restrict__ type_, const float* __restrict__ mask_,
                      const float* __restrict__ logits, const float* __restrict__ h0,
                      const float* __restrict__ mW1, const float* __restrict__ mb1,
                      const float* __restrict__ mW2, const float* __restrict__ mb2,
                      const float* __restrict__ jW1, const float* __restrict__ jb1,
                      const float* __restrict__ jW2, const float* __restrict__ jb2,
                      const float* __restrict__ eW1, const float* __restrict__ eb1,
                      const float* __restrict__ eW2, const float* __restrict__ eb2,
                      const float* __restrict__ hsrc, float* __restrict__ hdst,
                      float* __restrict__ acc, float* __restrict__ ltlog,
                      float* __restrict__ dout, int s) {
  __shared__ float xls[4][64];
  __shared__ float als[4][64];
  const int w = threadIdx.x >> 6, lane = threadIdx.x & 63;
  const int row = blockIdx.x * 4 + w;
  const int b = row / V_, v = row % V_;
  const int ev = type_[b * S_ + s];

  if (s == 0) {
    // l0 = e_int(broadcast(h0)) ; lt0 ; acc init
    const float eb1r = eb1[lane], eW2r = eW2[lane], eb2r = eb2[0];
    if (lane < 32) xls[w][lane] = h0[v * HD_ + lane];
    float a = dotWxT<8, 64>(eW1, xls[w], eb1r, lane);
    float t = tanhf(a) * eW2r;
#pragma unroll
    for (int o = 1; o < 64; o <<= 1) t += __shfl_xor(t, o, 64);
    float l0 = softplus_f(t + eb2r);
    if (lane == 0) {
      dout[1 + (b * S_ + 0) * V_ + v] = l0;
      acc[row] = 0.0f;
      if (v == ev) ltlog[0 * B_ + b] = logf(l0 + 1e-16f) * mask_[b * S_ + 0];
    }
  }

  const float mb1r = mb1[lane], jb1r = jb1[lane];
  const float mb2r = (lane < 32) ? mb2[lane] : 0.0f;
  const float jb2r = (lane < 32) ? jb2[lane] : 0.0f;

  if (lane < 32) {
    xls[w][lane]      = (s == 0) ? h0[ev * HD_ + lane] : hsrc[(b * V_ + ev) * HD_ + lane];
    xls[w][32 + lane] = (s == 0) ? h0[v * HD_ + lane]  : hsrc[row * HD_ + lane];
  }
  float a = dotWxT<16, 64>(mW1, xls[w], mb1r, lane);
  als[w][lane] = tanhf(a);

  float p;
  {
    int idx = ev * V_ + v;
    float l0v = logits[idx], l1v = logits[V_ * V_ + idx];
    float mx = fmaxf(l0v, l1v);
    float e0 = expf(l0v - mx), e1 = expf(l1v - mx);
    p = e1 / (e0 + e1);
  }
  float hn = 0.0f;
  if (lane < 32) {
    float mj = dotWxT<16, 32>(mW2, als[w], mb2r, lane);
    hn = xls[w][32 + lane] + mj * p;
  }
  if (v == ev) {  // owner row: jump on updated h (wave-uniform branch)
    if (lane < 32) xls[w][lane] = hn;
    float aj = dotWxT<8, 64>(jW1, xls[w], jb1r, lane);
    als[w][lane] = tanhf(aj);
    if (lane < 32) {
      float jj = dotWxT<16, 32>(jW2, als[w], jb2r, lane);
      hn += jj;
    }
  }
  if (lane < 32) hdst[row * HD_ + lane] = hn;
}

// ---------------- deterministic final reduce ----------------
__global__ void reduce_k(const float* __restrict__ acc, const float* __restrict__ ltlog,
                         float* __restrict__ dout) {
  __shared__ double sh[512];
  int t = threadIdx.x;
  double ia = 0.0, st = 0.0;
  for (int i = t; i < NROW; i += 256) ia += (double)acc[i];
  for (int i = t; i < B_ * S_; i += 256) st += (double)ltlog[i];
  sh[t] = ia; sh[256 + t] = st;
  __syncthreads();
  for (int o = 128; o > 0; o >>= 1) {
    if (t < o) { sh[t] += sh[t + o]; sh[256 + t] += sh[256 + t + o]; }
    __syncthreads();
  }
  if (t == 0) dout[0] = (float)(0.5 * sh[0] - sh[256]);
}

extern "C" void kernel_launch(void* const* d_in, const int* in_sizes, int n_in,
                              void* d_out, int out_size, void* d_ws, size_t ws_size,
                              hipStream_t stream) {
  const float* time_  = (const float*)d_in[0];
  const int*   type_  = (const int*)d_in[1];
  const float* mask_  = (const float*)d_in[2];
  const float* logits = (const float*)d_in[3];
  const float* h0     = (const float*)d_in[4];
  const float* fW1 = (const float*)d_in[5];  const float* fb1 = (const float*)d_in[6];
  const float* fW2 = (const float*)d_in[7];  const float* fb2 = (const float*)d_in[8];
  const float* fW3 = (const float*)d_in[9];  const float* fb3 = (const float*)d_in[10];
  const float* gW1 = (const float*)d_in[11]; const float* gb1 = (const float*)d_in[12];
  const float* gW2 = (const float*)d_in[13]; const float* gb2 = (const float*)d_in[14];
  const float* gW3 = (const float*)d_in[15]; const float* gb3 = (const float*)d_in[16];
  const float* eW1 = (const float*)d_in[17]; const float* eb1 = (const float*)d_in[18];
  const float* eW2 = (const float*)d_in[19]; const float* eb2 = (const float*)d_in[20];
  const float* jW1 = (const float*)d_in[21]; const float* jb1 = (const float*)d_in[22];
  const float* jW2 = (const float*)d_in[23]; const float* jb2 = (const float*)d_in[24];
  const float* mW1 = (const float*)d_in[25]; const float* mb1 = (const float*)d_in[26];
  const float* mW2 = (const float*)d_in[27]; const float* mb2 = (const float*)d_in[28];
  float* out = (float*)d_out;

  float* hA    = (float*)d_ws;            // 102400
  float* hB    = hA + NROW * HD_;         // 102400
  float* acc   = hB + NROW * HD_;         // 3200
  float* prevl = acc + NROW;              // 3200
  float* prevt = prevl + NROW;            // 3200
  float* ltlog = prevt + NROW;            // 1024

  // host-side key chain: key(42); 310x (k, sub) = fold-like split(k)
  uint32_t kh = 0u, kl = 42u;
  static_assert((S_ - 1) * ND_ == 310, "chain len");
  uint32_t subs[310][2];
  for (int n = 0; n < 310; ++n) {
    uint32_t a0 = 0u, a1 = 0u; tf2x32(kh, kl, a0, a1);   // count (0,0) -> new key
    uint32_t b0 = 0u, b1 = 1u; tf2x32(kh, kl, b0, b1);   // count (0,1) -> subkey
    subs[n][0] = b0; subs[n][1] = b1;
    kh = a0; kl = a1;
  }

  dim3 grid(NROW / 4), blk(256);
  // K0 + msg_jump(ev0): writes hA
  msg_k<<<grid, blk, 0, stream>>>(type_, mask_, logits, h0,
                                  mW1, mb1, mW2, mb2, jW1, jb1, jW2, jb2,
                                  eW1, eb1, eW2, eb2,
                                  hA /*unused*/, hA, acc, ltlog, out, 0);
  for (int s = 1; s <= 31; ++s) {
    float* hcur = ((s - 1) & 1) ? hB : hA;
    SubK sk;
    for (int j = 0; j < ND_; ++j) {
      sk.k[j][0] = subs[(s - 1) * ND_ + j][0];
      sk.k[j][1] = subs[(s - 1) * ND_ + j][1];
    }
    euler_k<<<grid, blk, 0, stream>>>(time_, type_, mask_,
                                      fW1, fb1, fW2, fb2, fW3, fb3,
                                      gW1, gb1, gW2, gb2, gW3, gb3,
                                      eW1, eb1, eW2, eb2,
                                      hcur, acc, prevl, prevt, ltlog, out, s, sk);
    if (s < 31) {  // last msg_jump's h is never consumed by any output
      float* hdst = (s & 1) ? hB : hA;
      msg_k<<<grid, blk, 0, stream>>>(type_, mask_, logits, h0,
                                      mW1, mb1, mW2, mb2, jW1, jb1, jW2, jb2,
                                      eW1, eb1, eW2, eb2,
                                      hcur, hdst, acc, ltlog, out, s);
    }
  }
  reduce_k<<<1, 256, 0, stream>>>(acc, ltlog, out);
}

// Round 3
// 7055.654 us; speedup vs baseline: 1.6304x; 1.6304x over previous
//
#include <hip/hip_runtime.h>
#include <stdint.h>

#define B_  32
#define S_  32
#define V_  100
#define HD_ 32
#define HID_ 64
#define ND_ 10
#define NROW (B_*V_)

// ---- workspace float offsets ----
#define WO_LDS   0            // 40 chunks x 256 floats = 10240 (f1[0..7], g1[8..15], fg3[16..31], e1[32..39])
#define WO_FW1E  10240        // 2 x 64  (fW1 rows 32(dft),33(last))
#define WO_GW1E  10368        // 64      (gW1 row 32(dft))
#define WO_FW2T  10432        // 64x64 [o][k]
#define WO_GW2T  14528        // 64x64 [o][k]
#define WO_HA    18624
#define WO_HB    (WO_HA + NROW*HD_)
#define WO_ACC   (WO_HB + NROW*HD_)
#define WO_PREVL (WO_ACC + NROW)
#define WO_PREVT (WO_PREVL + NROW)
#define WO_LTLOG (WO_PREVT + NROW)

// ---------------- threefry2x32 (JAX-compatible) ----------------
__host__ __device__ inline void tf2x32(uint32_t k0, uint32_t k1,
                                       uint32_t& x0, uint32_t& x1) {
  uint32_t ks0 = k0, ks1 = k1, ks2 = k0 ^ k1 ^ 0x1BD11BDAu;
#define TFR(r) { x0 += x1; x1 = (x1 << (r)) | (x1 >> (32 - (r))); x1 ^= x0; }
  x0 += ks0; x1 += ks1;
  TFR(13) TFR(15) TFR(26) TFR(6)
  x0 += ks1; x1 += ks2 + 1u;
  TFR(17) TFR(29) TFR(16) TFR(24)
  x0 += ks2; x1 += ks0 + 2u;
  TFR(13) TFR(15) TFR(26) TFR(6)
  x0 += ks0; x1 += ks1 + 3u;
  TFR(17) TFR(29) TFR(16) TFR(24)
  x0 += ks1; x1 += ks2 + 4u;
  TFR(13) TFR(15) TFR(26) TFR(6)
  x0 += ks2; x1 += ks0 + 5u;
#undef TFR
}

// ---------------- erfinv (XLA / Giles f32 polynomial) — keep precise ----------------
__device__ __forceinline__ float erfinv_f(float x) {
  float w = -log1pf(-x * x);
  float p;
  if (w < 5.0f) {
    w -= 2.5f;
    p = 2.81022636e-08f;
    p = fmaf(p, w, 3.43273939e-07f);
    p = fmaf(p, w, -3.5233877e-06f);
    p = fmaf(p, w, -4.39150654e-06f);
    p = fmaf(p, w, 0.00021858087f);
    p = fmaf(p, w, -0.00125372503f);
    p = fmaf(p, w, -0.00417768164f);
    p = fmaf(p, w, 0.246640727f);
    p = fmaf(p, w, 1.50140941f);
  } else {
    w = sqrtf(w) - 3.0f;
    p = -0.000200214257f;
    p = fmaf(p, w, 0.000100950558f);
    p = fmaf(p, w, 0.00134934322f);
    p = fmaf(p, w, -0.00367342844f);
    p = fmaf(p, w, 0.00573950773f);
    p = fmaf(p, w, -0.0076224613f);
    p = fmaf(p, w, 0.00943887047f);
    p = fmaf(p, w, 1.00167406f);
    p = fmaf(p, w, 2.83297682f);
  }
  return p * x;
}

// ---------------- fast device math (errors ~1e-7 rel, far under 2% gate) ----
__device__ __forceinline__ float tanhf_fast(float x) {
  float ax = fabsf(x);
  float e  = __expf(-2.0f * ax);
  float r  = (1.0f - e) * __builtin_amdgcn_rcpf(1.0f + e);
  return copysignf(r, x);
}
__device__ __forceinline__ float softplus_fast(float x) {
  return fmaxf(x, 0.0f) + __logf(1.0f + __expf(-fabsf(x)));
}
__device__ __forceinline__ float rl(float v, int k) {
  return __uint_as_float(__builtin_amdgcn_readlane(__float_as_uint(v), (uint32_t)k));
}

// out = a + sum x[k]*W[k*O+lane] (used by msg_k only)
template<int K4, int O>
__device__ __forceinline__ float dotWxT(const float* __restrict__ W,
                                        const float* __restrict__ x,
                                        float a, int lane) {
#pragma unroll
  for (int kb = 0; kb < K4; ++kb) {
    float4 xv = *(const float4*)(x + kb * 4);
    a = fmaf(xv.x, W[(kb * 4 + 0) * O + lane], a);
    a = fmaf(xv.y, W[(kb * 4 + 1) * O + lane], a);
    a = fmaf(xv.z, W[(kb * 4 + 2) * O + lane], a);
    a = fmaf(xv.w, W[(kb * 4 + 3) * O + lane], a);
  }
  return a;
}

struct SubK { uint32_t k[ND_][2]; };

// ---------------- prep: transpose weights into ws ----------------
__global__ void prep_k(const float* __restrict__ fW1, const float* __restrict__ gW1,
                       const float* __restrict__ fW3, const float* __restrict__ gW3,
                       const float* __restrict__ eW1, const float* __restrict__ fW2,
                       const float* __restrict__ gW2, float* __restrict__ ws) {
  int i = blockIdx.x * 256 + threadIdx.x;
  if (i < 10240) {
    int c = i >> 8, r = i & 255, o = r >> 2, ii = r & 3;
    float v;
    if (c < 8)       v = fW1[(c * 4 + ii) * HID_ + o];
    else if (c < 16) v = gW1[((c - 8) * 4 + ii) * HID_ + o];
    else if (c < 32) { int k = (c - 16) * 4 + ii;
                       v = (o < 32) ? fW3[k * HD_ + o] : gW3[k * HD_ + (o - 32)]; }
    else             v = eW1[((c - 32) * 4 + ii) * HID_ + o];
    ws[WO_LDS + i] = v;
  } else if (i < 10368) { int j = i - 10240; ws[i] = fW1[(32 + (j >> 6)) * HID_ + (j & 63)]; }
  else if (i < 10432)   { ws[i] = gW1[32 * HID_ + (i - 10368)]; }
  else if (i < 14528)   { int j = i - 10432; ws[i] = fW2[(j & 63) * HID_ + (j >> 6)]; }
  else if (i < 18624)   { int j = i - 14528; ws[i] = gW2[(j & 63) * HID_ + (j >> 6)]; }
}

// ---------------- Euler kernel: one interval, 1 row/wave ----------------
__launch_bounds__(256)
__global__ void euler_k(const float* __restrict__ time_, const int* __restrict__ type_,
                        const float* __restrict__ mask_, const float* __restrict__ ws,
                        const float* __restrict__ fb1, const float* __restrict__ fb2,
                        const float* __restrict__ fb3, const float* __restrict__ gb1,
                        const float* __restrict__ gb2, const float* __restrict__ gb3,
                        const float* __restrict__ eb1, const float* __restrict__ eW2,
                        const float* __restrict__ eb2,
                        float* __restrict__ h, float* __restrict__ acc,
                        float* __restrict__ prevl, float* __restrict__ prevt,
                        float* __restrict__ ltlog, float* __restrict__ dout,
                        int s, SubK sk) {
  __shared__ float lds[10240];
  const int w = threadIdx.x >> 6, lane = threadIdx.x & 63;
  const int row = blockIdx.x * 4 + w;
  const int b = row / V_, v = row - b * V_;
  const bool lo = (lane < 32);

  { // stage small-layer weights to LDS (chunk-major, conflict-free)
    const float4* src = (const float4*)(ws + WO_LDS);
    float4* dst = (float4*)lds;
    for (int t = threadIdx.x; t < 2560; t += 256) dst[t] = src[t];
  }

  // layer-2 weight columns in registers (fully static indexing)
  float w2f[64], w2g[64];
  {
    const float* f2 = ws + WO_FW2T + lane * 64;
    const float* g2 = ws + WO_GW2T + lane * 64;
#pragma unroll
    for (int c = 0; c < 16; ++c) {
      float4 a = *(const float4*)(f2 + c * 4);
      w2f[4*c+0]=a.x; w2f[4*c+1]=a.y; w2f[4*c+2]=a.z; w2f[4*c+3]=a.w;
      float4 g = *(const float4*)(g2 + c * 4);
      w2g[4*c+0]=g.x; w2g[4*c+1]=g.y; w2g[4*c+2]=g.z; w2g[4*c+3]=g.w;
    }
  }

  const float fb1r = fb1[lane], fb2r = fb2[lane];
  const float gb1r = gb1[lane], gb2r = gb2[lane];
  const float eb1r = eb1[lane], eW2r = eW2[lane], eb2r = eb2[0];
  const float b3r  = lo ? fb3[lane] : gb3[lane - 32];
  const float fe0 = ws[WO_FW1E + lane], fe1 = ws[WO_FW1E + 64 + lane];
  const float ge0 = ws[WO_GW1E + lane];

  const float t0 = time_[b * S_ + s - 1];
  const float t1 = time_[b * S_ + s];
  const float dt = (t1 - t0) / 10.0f;
  const float sq = sqrtf(dt);
  const float msk  = mask_[b * S_ + s];
  const float mskp = mask_[b * S_ + s - 1];
  float hreg = h[row * HD_ + (lane & 31)];   // both halves mirror h

  __syncthreads();

  auto eint = [&]() -> float {
    float a = eb1r;
#pragma unroll
    for (int c = 0; c < 8; ++c) {
      const float4 we = *(const float4*)&lds[((32 + c) * 64 + lane) * 4];
      a = fmaf(rl(hreg, 4*c+0), we.x, a);
      a = fmaf(rl(hreg, 4*c+1), we.y, a);
      a = fmaf(rl(hreg, 4*c+2), we.z, a);
      a = fmaf(rl(hreg, 4*c+3), we.w, a);
    }
    float t = tanhf_fast(a) * eW2r;
#pragma unroll
    for (int o = 1; o < 64; o <<= 1) t += __shfl_xor(t, o, 64);
    return softplus_fast(t + eb2r);
  };

  float lprev = eint();
  float accl = acc[row];
  if (s > 1) accl += (prevl[row] * mskp + lprev * msk) * (t0 - prevt[row]) * msk;

#pragma unroll 1
  for (int j = 0; j < ND_; ++j) {
    const float dft = dt * (float)(j + 1);
    // ---- layer 1, f & g interleaved, x = hreg via readlane ----
    float af = fb1r, ag = gb1r;
#pragma unroll
    for (int c = 0; c < 8; ++c) {
      const float4 wf = *(const float4*)&lds[((0 + c) * 64 + lane) * 4];
      const float4 wg = *(const float4*)&lds[((8 + c) * 64 + lane) * 4];
      float s0 = rl(hreg, 4*c+0), s1 = rl(hreg, 4*c+1);
      float s2 = rl(hreg, 4*c+2), s3 = rl(hreg, 4*c+3);
      af = fmaf(s0, wf.x, af); ag = fmaf(s0, wg.x, ag);
      af = fmaf(s1, wf.y, af); ag = fmaf(s1, wg.y, ag);
      af = fmaf(s2, wf.z, af); ag = fmaf(s2, wg.z, ag);
      af = fmaf(s3, wf.w, af); ag = fmaf(s3, wg.w, ag);
    }
    af = fmaf(dft, fe0, af); af = fmaf(t0, fe1, af);
    ag = fmaf(dft, ge0, ag);
    float xf = tanhf_fast(af), xg = tanhf_fast(ag);
    // ---- layer 2, weights in VGPRs ----
    float bf = fb2r, bg = gb2r;
#pragma unroll
    for (int k = 0; k < 64; ++k) {
      bf = fmaf(rl(xf, k), w2f[k], bf);
      bg = fmaf(rl(xg, k), w2g[k], bg);
    }
    xf = tanhf_fast(bf); xg = tanhf_fast(bg);
    // ---- layer 3: lanes<32 -> f3 (drift), lanes>=32 -> g3 (diff) ----
    float a3 = b3r;
#pragma unroll
    for (int c = 0; c < 16; ++c) {
      const float4 wc = *(const float4*)&lds[((16 + c) * 64 + lane) * 4];
      float p0 = lo ? rl(xf, 4*c+0) : rl(xg, 4*c+0);
      float p1 = lo ? rl(xf, 4*c+1) : rl(xg, 4*c+1);
      float p2 = lo ? rl(xf, 4*c+2) : rl(xg, 4*c+2);
      float p3 = lo ? rl(xf, 4*c+3) : rl(xg, 4*c+3);
      a3 = fmaf(p0, wc.x, a3); a3 = fmaf(p1, wc.y, a3);
      a3 = fmaf(p2, wc.z, a3); a3 = fmaf(p3, wc.w, a3);
    }
    // ---- exchange drift/diff across halves; both halves update h ----
    float part  = __shfl_xor(a3, 32, 64);
    float drift = lo ? a3 : part;
    float diff  = lo ? part : a3;
    const int i = lane & 31;
    uint32_t x0 = 0u, x1 = (uint32_t)(row * HD_ + i);
    tf2x32(sk.k[j][0], sk.k[j][1], x0, x1);
    uint32_t bits = x0 ^ x1;
    float fr = __uint_as_float(0x3f800000u | (bits >> 9)) - 1.0f;
    const float LOW = -0.99999994f;
    float u = fmaxf(LOW, fr * 2.0f + LOW);
    float n = 1.4142135f * erfinv_f(u);
    hreg = hreg + drift * dt + (diff * sq) * n;
    // ---- intensity + trapezoid ----
    float l = eint();
    float tj  = t0 + dt * (float)j;
    float tj1 = t0 + dt * (float)(j + 1);
    accl += (lprev * msk + l * msk) * ((tj1 - tj) * msk);
    lprev = l;
  }

  if (lo) h[row * HD_ + lane] = hreg;
  if (lane == 0) {
    acc[row] = accl;
    prevl[row] = lprev;
    prevt[row] = t0 + dt * 10.0f;
    dout[1 + (b * S_ + s) * V_ + v] = lprev;
    int ev = type_[b * S_ + s];
    if (v == ev) ltlog[s * B_ + b] = logf(lprev + 1e-16f) * msk;
  }
}

// ---------------- msg_jump kernel (unchanged from passing round 1) ----------------
__launch_bounds__(256)
__global__ void msg_k(const int* __restrict__ type_, const float* __restrict__ mask_,
                      const float* __restrict__ logits, const float* __restrict__ h0,
                      const float* __restrict__ mW1, const float* __restrict__ mb1,
                      const float* __restrict__ mW2, const float* __restrict__ mb2,
                      const float* __restrict__ jW1, const float* __restrict__ jb1,
                      const float* __restrict__ jW2, const float* __restrict__ jb2,
                      const float* __restrict__ eW1, const float* __restrict__ eb1,
                      const float* __restrict__ eW2, const float* __restrict__ eb2,
                      const float* __restrict__ hsrc, float* __restrict__ hdst,
                      float* __restrict__ acc, float* __restrict__ ltlog,
                      float* __restrict__ dout, int s) {
  __shared__ float xls[4][64];
  __shared__ float als[4][64];
  const int w = threadIdx.x >> 6, lane = threadIdx.x & 63;
  const int row = blockIdx.x * 4 + w;
  const int b = row / V_, v = row % V_;
  const int ev = type_[b * S_ + s];

  if (s == 0) {
    const float eb1r = eb1[lane], eW2r = eW2[lane], eb2r = eb2[0];
    if (lane < 32) xls[w][lane] = h0[v * HD_ + lane];
    float a = dotWxT<8, 64>(eW1, xls[w], eb1r, lane);
    float t = tanhf(a) * eW2r;
#pragma unroll
    for (int o = 1; o < 64; o <<= 1) t += __shfl_xor(t, o, 64);
    float l0 = fmaxf(t + eb2r, 0.0f) + log1pf(expf(-fabsf(t + eb2r)));
    if (lane == 0) {
      dout[1 + (b * S_ + 0) * V_ + v] = l0;
      acc[row] = 0.0f;
      if (v == ev) ltlog[0 * B_ + b] = logf(l0 + 1e-16f) * mask_[b * S_ + 0];
    }
  }

  const float mb1r = mb1[lane], jb1r = jb1[lane];
  const float mb2r = (lane < 32) ? mb2[lane] : 0.0f;
  const float jb2r = (lane < 32) ? jb2[lane] : 0.0f;

  if (lane < 32) {
    xls[w][lane]      = (s == 0) ? h0[ev * HD_ + lane] : hsrc[(b * V_ + ev) * HD_ + lane];
    xls[w][32 + lane] = (s == 0) ? h0[v * HD_ + lane]  : hsrc[row * HD_ + lane];
  }
  float a = dotWxT<16, 64>(mW1, xls[w], mb1r, lane);
  als[w][lane] = tanhf(a);

  float p;
  {
    int idx = ev * V_ + v;
    float l0v = logits[idx], l1v = logits[V_ * V_ + idx];
    float mx = fmaxf(l0v, l1v);
    float e0 = expf(l0v - mx), e1 = expf(l1v - mx);
    p = e1 / (e0 + e1);
  }
  float hn = 0.0f;
  if (lane < 32) {
    float mj = dotWxT<16, 32>(mW2, als[w], mb2r, lane);
    hn = xls[w][32 + lane] + mj * p;
  }
  if (v == ev) {
    if (lane < 32) xls[w][lane] = hn;
    float aj = dotWxT<8, 64>(jW1, xls[w], jb1r, lane);
    als[w][lane] = tanhf(aj);
    if (lane < 32) {
      float jj = dotWxT<16, 32>(jW2, als[w], jb2r, lane);
      hn += jj;
    }
  }
  if (lane < 32) hdst[row * HD_ + lane] = hn;
}

// ---------------- deterministic final reduce ----------------
__global__ void reduce_k(const float* __restrict__ acc, const float* __restrict__ ltlog,
                         float* __restrict__ dout) {
  __shared__ double sh[512];
  int t = threadIdx.x;
  double ia = 0.0, st = 0.0;
  for (int i = t; i < NROW; i += 256) ia += (double)acc[i];
  for (int i = t; i < B_ * S_; i += 256) st += (double)ltlog[i];
  sh[t] = ia; sh[256 + t] = st;
  __syncthreads();
  for (int o = 128; o > 0; o >>= 1) {
    if (t < o) { sh[t] += sh[t + o]; sh[256 + t] += sh[256 + t + o]; }
    __syncthreads();
  }
  if (t == 0) dout[0] = (float)(0.5 * sh[0] - sh[256]);
}

extern "C" void kernel_launch(void* const* d_in, const int* in_sizes, int n_in,
                              void* d_out, int out_size, void* d_ws, size_t ws_size,
                              hipStream_t stream) {
  const float* time_  = (const float*)d_in[0];
  const int*   type_  = (const int*)d_in[1];
  const float* mask_  = (const float*)d_in[2];
  const float* logits = (const float*)d_in[3];
  const float* h0     = (const float*)d_in[4];
  const float* fW1 = (const float*)d_in[5];  const float* fb1 = (const float*)d_in[6];
  const float* fW2 = (const float*)d_in[7];  const float* fb2 = (const float*)d_in[8];
  const float* fW3 = (const float*)d_in[9];  const float* fb3 = (const float*)d_in[10];
  const float* gW1 = (const float*)d_in[11]; const float* gb1 = (const float*)d_in[12];
  const float* gW2 = (const float*)d_in[13]; const float* gb2 = (const float*)d_in[14];
  const float* gW3 = (const float*)d_in[15]; const float* gb3 = (const float*)d_in[16];
  const float* eW1 = (const float*)d_in[17]; const float* eb1 = (const float*)d_in[18];
  const float* eW2 = (const float*)d_in[19]; const float* eb2 = (const float*)d_in[20];
  const float* jW1 = (const float*)d_in[21]; const float* jb1 = (const float*)d_in[22];
  const float* jW2 = (const float*)d_in[23]; const float* jb2 = (const float*)d_in[24];
  const float* mW1 = (const float*)d_in[25]; const float* mb1 = (const float*)d_in[26];
  const float* mW2 = (const float*)d_in[27]; const float* mb2 = (const float*)d_in[28];
  float* out = (float*)d_out;

  float* ws    = (float*)d_ws;
  float* hA    = ws + WO_HA;
  float* hB    = ws + WO_HB;
  float* acc   = ws + WO_ACC;
  float* prevl = ws + WO_PREVL;
  float* prevt = ws + WO_PREVT;
  float* ltlog = ws + WO_LTLOG;

  // host-side key chain: key(42); 310x fold-like split
  uint32_t kh = 0u, kl = 42u;
  uint32_t subs[310][2];
  for (int n = 0; n < 310; ++n) {
    uint32_t a0 = 0u, a1 = 0u; tf2x32(kh, kl, a0, a1);
    uint32_t b0 = 0u, b1 = 1u; tf2x32(kh, kl, b0, b1);
    subs[n][0] = b0; subs[n][1] = b1;
    kh = a0; kl = a1;
  }

  prep_k<<<73, 256, 0, stream>>>(fW1, gW1, fW3, gW3, eW1, fW2, gW2, ws);

  dim3 grid(NROW / 4), blk(256);
  msg_k<<<grid, blk, 0, stream>>>(type_, mask_, logits, h0,
                                  mW1, mb1, mW2, mb2, jW1, jb1, jW2, jb2,
                                  eW1, eb1, eW2, eb2,
                                  hA, hA, acc, ltlog, out, 0);
  for (int s = 1; s <= 31; ++s) {
    float* hcur = ((s - 1) & 1) ? hB : hA;
    SubK sk;
    for (int j = 0; j < ND_; ++j) {
      sk.k[j][0] = subs[(s - 1) * ND_ + j][0];
      sk.k[j][1] = subs[(s - 1) * ND_ + j][1];
    }
    euler_k<<<grid, blk, 0, stream>>>(time_, type_, mask_, ws,
                                      fb1, fb2, fb3, gb1, gb2, gb3,
                                      eb1, eW2, eb2,
                                      hcur, acc, prevl, prevt, ltlog, out, s, sk);
    if (s < 31) {
      float* hdst = (s & 1) ? hB : hA;
      msg_k<<<grid, blk, 0, stream>>>(type_, mask_, logits, h0,
                                      mW1, mb1, mW2, mb2, jW1, jb1, jW2, jb2,
                                      eW1, eb1, eW2, eb2,
                                      hcur, hdst, acc, ltlog, out, s);
    }
  }
  reduce_k<<<1, 256, 0, stream>>>(acc, ltlog, out);
}